// Round 3
// baseline (576.087 us; speedup 1.0000x reference)
//
#include <hip/hip_runtime.h>
#include <math.h>

#define EPS 1e-5f
constexpr int IMG_H = 1024;
constexpr int IMG_W = 1024;
constexpr int NIMG  = 32;

__device__ __forceinline__ float frelu(float v) { return fmaxf(v, 0.f); }

struct Row { float4 q[4]; };

__device__ __forceinline__ void load_row(const float* __restrict__ xim, int gr,
                                         int lane, Row& R)
{
    if ((unsigned)gr < (unsigned)IMG_H) {
        const float4* rp = (const float4*)(xim + (size_t)gr * IMG_W);
#pragma unroll
        for (int q = 0; q < 4; ++q) R.q[q] = rp[lane + 64 * q];
    } else {
#pragma unroll
        for (int q = 0; q < 4; ++q) R.q[q] = make_float4(0.f, 0.f, 0.f, 0.f);
    }
}

// conv3x3 (bn-folded weights ws, bias) of one full 1024-wide row held across a
// wave as 4 float4 chunks/lane; neighbors via shfl.
__device__ __forceinline__ void conv3_row(const Row& Ra, const Row& Rb, const Row& Rc,
                                          const float* ws, float bias, int lane,
                                          float4* v)
{
    const Row* rows[3] = { &Ra, &Rb, &Rc };
#pragma unroll
    for (int q = 0; q < 4; ++q) {
        float acc0 = bias, acc1 = bias, acc2 = bias, acc3 = bias;
#pragma unroll
        for (int dy = 0; dy < 3; ++dy) {
            float4 C = rows[dy]->q[q];
            float Lw = __shfl_up(C.w, 1, 64);
            float Bq = 0.f;
            if (q > 0) Bq = __shfl(rows[dy]->q[q - 1].w, 63, 64);
            if (lane == 0) Lw = Bq;
            float Rx = __shfl_down(C.x, 1, 64);
            float Aq = 0.f;
            if (q < 3) Aq = __shfl(rows[dy]->q[q + 1].x, 0, 64);
            if (lane == 63) Rx = Aq;
            const float w0 = ws[3 * dy], w1 = ws[3 * dy + 1], w2 = ws[3 * dy + 2];
            acc0 += w0 * Lw  + w1 * C.x + w2 * C.y;
            acc1 += w0 * C.x + w1 * C.y + w2 * C.z;
            acc2 += w0 * C.y + w1 * C.z + w2 * C.w;
            acc3 += w0 * C.z + w1 * C.w + w2 * Rx;
        }
        v[q] = make_float4(frelu(acc0), frelu(acc1), frelu(acc2), frelu(acc3));
    }
}

// ===========================================================================
// K1: per 16-row group (4 waves x 4 rows, rolling loads): compute x1 rows,
// write M8 (8-row column max) and I1S (row suffix-max sampled at cols 64k+3).
// ===========================================================================
__global__ __launch_bounds__(256) void k_rowstats(
    const float* __restrict__ x,
    const float* __restrict__ wa, const float* __restrict__ ba,
    const float* __restrict__ ga, const float* __restrict__ bta,
    const float* __restrict__ ma, const float* __restrict__ va,
    float* __restrict__ M8, float* __restrict__ I1S)
{
    const int bid  = blockIdx.x;           // 32 img * 64 groups
    const int img  = bid >> 6;
    const int b16  = bid & 63;
    const int lane = threadIdx.x & 63;
    const int wv   = threadIdx.x >> 6;
    const int rb   = b16 * 16 + wv * 4;

    const float scale = ga[0] * rsqrtf(va[0] + EPS);
    float w_s[9];
#pragma unroll
    for (int k = 0; k < 9; ++k) w_s[k] = wa[k] * scale;
    const float bias = (ba[0] - ma[0]) * scale + bta[0];

    const float* xim = x + (size_t)img * IMG_H * IMG_W;

    Row A, B, C;
    load_row(xim, rb - 1, lane, A);
    load_row(xim, rb,     lane, B);

    float4 cm[4];
#pragma unroll
    for (int q = 0; q < 4; ++q) cm[q] = make_float4(0.f, 0.f, 0.f, 0.f);

#pragma unroll
    for (int rr = 0; rr < 4; ++rr) {
        const int r = rb + rr;
        load_row(xim, r + 1, lane, C);
        float4 v[4];
        conv3_row(A, B, C, w_s, bias, lane, v);

        // row suffix-max structures
        float4 s[4]; float T4[4], e[4];
#pragma unroll
        for (int q = 0; q < 4; ++q) {
            float s3 = v[q].w;
            float s2 = fmaxf(v[q].z, s3);
            float s1 = fmaxf(v[q].y, s2);
            float s0 = fmaxf(v[q].x, s1);
            s[q] = make_float4(s0, s1, s2, s3);
            float mm = s0;
#pragma unroll
            for (int off = 1; off < 64; off <<= 1) {
                float o = __shfl_down(mm, off, 64);
                if (lane + off < 64) mm = fmaxf(mm, o);
            }
            T4[q] = __shfl(mm, 0, 64);
            float ex = __shfl_down(mm, 1, 64);
            if (lane == 63) ex = -INFINITY;
            e[q] = ex;
        }
        float Rr[4];
        Rr[3] = -INFINITY;
        Rr[2] = T4[3];
        Rr[1] = fmaxf(T4[2], Rr[2]);
        Rr[0] = fmaxf(T4[1], Rr[1]);

        if ((lane & 15) == 0) {
#pragma unroll
            for (int q = 0; q < 4; ++q) {
                const float ee  = fmaxf(e[q], Rr[q]);
                const float i1w = fmaxf(s[q].w, ee);   // i1 at col 256q+4*lane+3
                I1S[((size_t)img * IMG_H + r) * 16 + (q * 4 + (lane >> 4))] = i1w;
            }
        }
#pragma unroll
        for (int q = 0; q < 4; ++q) {
            cm[q].x = fmaxf(cm[q].x, v[q].x); cm[q].y = fmaxf(cm[q].y, v[q].y);
            cm[q].z = fmaxf(cm[q].z, v[q].z); cm[q].w = fmaxf(cm[q].w, v[q].w);
        }
        A = B; B = C;
    }

    __shared__ float4 wcm[4][256];
#pragma unroll
    for (int q = 0; q < 4; ++q) wcm[wv][64 * q + lane] = cm[q];
    __syncthreads();

    const int tid = threadIdx.x;
    float4 a0 = wcm[0][tid], a1 = wcm[1][tid];
    float4 a2 = wcm[2][tid], a3 = wcm[3][tid];
    float4 f0 = make_float4(fmaxf(a0.x, a1.x), fmaxf(a0.y, a1.y),
                            fmaxf(a0.z, a1.z), fmaxf(a0.w, a1.w));
    float4 f1 = make_float4(fmaxf(a2.x, a3.x), fmaxf(a2.y, a3.y),
                            fmaxf(a2.z, a3.z), fmaxf(a2.w, a3.w));
    const int s0 = b16 * 2;
    ((float4*)(M8 + ((size_t)img * 128 + s0) * IMG_W))[tid]     = f0;
    ((float4*)(M8 + ((size_t)img * 128 + s0 + 1) * IMG_W))[tid] = f1;
}

// ===========================================================================
// K2: bottom-up suffix over 128 strip maxes; emit I2S(m,c) = suffix over
// strips > 8m+8 (i.e. rows >= 64m+72), for m = 0..14.
// ===========================================================================
__global__ __launch_bounds__(256) void k_seed(
    const float* __restrict__ M8, float* __restrict__ I2S)
{
    const int gid = blockIdx.x * 256 + threadIdx.x;   // 32768
    const int img = gid >> 10;
    const int c   = gid & 1023;
    const float* mp = M8  + (size_t)img * 128 * IMG_W + c;
    float*       ip = I2S + (size_t)img * 16  * IMG_W + c;

    float run = 0.f;
#pragma unroll 8
    for (int s = 127; s >= 8; --s) {
        if ((s & 7) == 0) ip[(size_t)(s / 8 - 1) * IMG_W] = run;
        run = fmaxf(run, mp[(size_t)s * IMG_W]);
    }
}

// ===========================================================================
// K3: mega-tile. Per 64x64 output tile:
//   P1: x1 (75x70) into B1 from global x
//   P2: i1 row-suffix (wave-parallel shfl) seeded from I1S -> B2
//   P3: i2 column scan over B1 (rows 74..0) seeded from I2S; B2 = t (masked)
//   P4: s  = relu(bn(conv_wb(t)) + x*kc + biasc)  (68x68) -> B1
//   P5: a1 = relu(bn(conv_wa(s)))                 (66x66) -> B2
//   P6: out= conv1x1_we(relu(conv_wd(a1)+bd))     (64x64) -> global
// ===========================================================================
__global__ __launch_bounds__(256) void k_tile(
    const float* __restrict__ x,
    const float* __restrict__ I1S, const float* __restrict__ I2S,
    const float* __restrict__ wa, const float* __restrict__ ba,
    const float* __restrict__ ga, const float* __restrict__ bta,
    const float* __restrict__ ma, const float* __restrict__ va,
    const float* __restrict__ wb, const float* __restrict__ bb,
    const float* __restrict__ gb, const float* __restrict__ btb,
    const float* __restrict__ mb, const float* __restrict__ vb,
    const float* __restrict__ wc, const float* __restrict__ bc,
    const float* __restrict__ gcp, const float* __restrict__ btc,
    const float* __restrict__ mc, const float* __restrict__ vc,
    const float* __restrict__ wd, const float* __restrict__ bd,
    const float* __restrict__ we, const float* __restrict__ be,
    float* __restrict__ out)
{
    __shared__ float B1[75 * 72];
    __shared__ float B2[70 * 72];

    const int bid = blockIdx.x;
    const int img = bid >> 8;
    const int tr  = (bid >> 4) & 15;
    const int tc  = bid & 15;
    const int r0  = tr * 64, c0 = tc * 64;
    const int tid = threadIdx.x;
    const int k0  = tc + 1;      // I1S column index (16 -> seed 0)
    const int m1  = tr;          // I2S row index   (15 -> seed 0)

    const float sa = ga[0] * rsqrtf(va[0] + EPS);
    float was[9];
#pragma unroll
    for (int k = 0; k < 9; ++k) was[k] = wa[k] * sa;
    const float biasa = (ba[0] - ma[0]) * sa + bta[0];

    const float sb = gb[0] * rsqrtf(vb[0] + EPS);
    float wbs[9];
#pragma unroll
    for (int k = 0; k < 9; ++k) wbs[k] = wb[k] * sb;
    const float biasb = (bb[0] - mb[0]) * sb + btb[0];

    const float sc = gcp[0] * rsqrtf(vc[0] + EPS);
    const float kc = wc[0] * sc;
    const float biasc = (bc[0] - mc[0]) * sc + btc[0];

    float wd9[9];
#pragma unroll
    for (int k = 0; k < 9; ++k) wd9[k] = wd[k];
    const float bd0 = bd[0], we0 = we[0], be0 = be[0];

    const float* xim = x + (size_t)img * IMG_H * IMG_W;

    // ---- P1: x1 window 75 rows x 70 cols, minis 5x4 (15x18 = 270)
#pragma unroll
    for (int it = 0; it < 2; ++it) {
        const int m = tid + 256 * it;
        if (m < 270) {
            const int mi = m / 18, mj = m - mi * 18;
            const int wr0 = mi * 5, wc0 = mj * 4;
            const int gr0 = r0 + wr0 - 4;
            const int gc0 = c0 + wc0 - 4;
            const bool fastC = (gc0 >= 0) && (gc0 + 5 < IMG_W);
            float w[7][6];
#pragma unroll
            for (int rr = 0; rr < 7; ++rr) {
                const int gr = gr0 + rr;
                if ((unsigned)gr < (unsigned)IMG_H) {
                    const float* rp = xim + (size_t)gr * IMG_W;
                    if (fastC) {
                        float4 a4 = *(const float4*)(rp + gc0);
                        float2 b2 = *(const float2*)(rp + gc0 + 4);
                        w[rr][0] = a4.x; w[rr][1] = a4.y; w[rr][2] = a4.z;
                        w[rr][3] = a4.w; w[rr][4] = b2.x; w[rr][5] = b2.y;
                    } else {
#pragma unroll
                        for (int j = 0; j < 6; ++j) {
                            const int gc = gc0 + j;
                            w[rr][j] = ((unsigned)gc < (unsigned)IMG_W) ? rp[gc] : 0.f;
                        }
                    }
                } else {
#pragma unroll
                    for (int j = 0; j < 6; ++j) w[rr][j] = 0.f;
                }
            }
#pragma unroll
            for (int rr = 0; rr < 5; ++rr) {
                const int grx = r0 - 3 + wr0 + rr;
                float res4[4];
#pragma unroll
                for (int cc = 0; cc < 4; ++cc) {
                    float acc = biasa;
#pragma unroll
                    for (int dy = 0; dy < 3; ++dy)
#pragma unroll
                        for (int dx = 0; dx < 3; ++dx)
                            acc += was[3 * dy + dx] * w[rr + dy][cc + dx];
                    const int gcx = c0 - 3 + wc0 + cc;
                    float val = 0.f;
                    if ((unsigned)grx < (unsigned)IMG_H && (unsigned)gcx < (unsigned)IMG_W)
                        val = frelu(acc);
                    res4[cc] = val;
                }
                *(float4*)&B1[(wr0 + rr) * 72 + wc0] =
                    make_float4(res4[0], res4[1], res4[2], res4[3]);
            }
        }
    }
    __syncthreads();

    // ---- P2: i1 row suffix (wave-parallel), rows 0..69 -> B2
    {
        const int wv = tid >> 6, lane = tid & 63;
#pragma unroll
        for (int k = 0; k < 18; ++k) {
            const int wr = k * 4 + wv;
            if (wr < 70) {
                const int row = r0 - 3 + wr;
                float seed = 0.f;
                if (k0 < 16 && (unsigned)row < (unsigned)IMG_H)
                    seed = I1S[((size_t)img * IMG_H + row) * 16 + k0];
                const float lo = B1[wr * 72 + lane];
                const float hi = (lane < 6) ? B1[wr * 72 + 64 + lane] : 0.f;
                float sh = hi;
#pragma unroll
                for (int off = 1; off < 64; off <<= 1) {
                    float o = __shfl_down(sh, off, 64);
                    if (lane + off < 64) sh = fmaxf(sh, o);
                }
                sh = fmaxf(sh, seed);
                const float hi_all = __shfl(sh, 0, 64);
                float sl = lo;
#pragma unroll
                for (int off = 1; off < 64; off <<= 1) {
                    float o = __shfl_down(sl, off, 64);
                    if (lane + off < 64) sl = fmaxf(sl, o);
                }
                B2[wr * 72 + lane] = fmaxf(sl, hi_all);
                if (lane < 6) B2[wr * 72 + 64 + lane] = sh;
            }
        }
    }
    __syncthreads();

    // ---- P3: i2 column scan (thread per col), t = i1+i2 masked -> B2
    if (tid < 70) {
        const int col = c0 - 3 + tid;
        const bool colIn = (unsigned)col < (unsigned)IMG_W;
        float run = 0.f;
        if (m1 < 15 && colIn) run = I2S[((size_t)img * 16 + m1) * IMG_W + col];
#pragma unroll
        for (int wr = 74; wr >= 70; --wr) run = fmaxf(run, B1[wr * 72 + tid]);
#pragma unroll 7
        for (int wr = 69; wr >= 0; --wr) {
            run = fmaxf(run, B1[wr * 72 + tid]);
            const int r = r0 - 3 + wr;
            const bool inb = colIn && ((unsigned)r < (unsigned)IMG_H);
            const float tv = B2[wr * 72 + tid] + run;
            B2[wr * 72 + tid] = inb ? tv : 0.f;
        }
    }
    __syncthreads();

    // ---- P4: s (68x68) -> B1 ; reads t from B2 + x pointwise
#pragma unroll
    for (int it = 0; it < 2; ++it) {
        const int m = tid + 256 * it;
        if (m < 289) {
            const int mi = m / 17, mj = m - mi * 17;
            const int si0 = mi * 4, sj0 = mj * 4;
            float win[6][6];
#pragma unroll
            for (int r = 0; r < 6; ++r) {
                const float* p = &B2[(si0 + r) * 72 + sj0];
                float4 a4 = *(const float4*)p;
                float2 b2 = *(const float2*)(p + 4);
                win[r][0] = a4.x; win[r][1] = a4.y; win[r][2] = a4.z;
                win[r][3] = a4.w; win[r][4] = b2.x; win[r][5] = b2.y;
            }
#pragma unroll
            for (int a = 0; a < 4; ++a) {
                float res4[4];
#pragma unroll
                for (int b = 0; b < 4; ++b) {
                    float acc = biasb;
#pragma unroll
                    for (int dy = 0; dy < 3; ++dy)
#pragma unroll
                        for (int dx = 0; dx < 3; ++dx)
                            acc += wbs[3 * dy + dx] * win[a + dy][b + dx];
                    const int gr = r0 - 2 + si0 + a, gc = c0 - 2 + sj0 + b;
                    float sres = 0.f;
                    if ((unsigned)gr < (unsigned)IMG_H && (unsigned)gc < (unsigned)IMG_W) {
                        const float xv = xim[(size_t)gr * IMG_W + gc];
                        sres = frelu(acc + xv * kc + biasc);
                    }
                    res4[b] = sres;
                }
                *(float4*)&B1[(si0 + a) * 72 + sj0] =
                    make_float4(res4[0], res4[1], res4[2], res4[3]);
            }
        }
    }
    __syncthreads();

    // ---- P5: a1 (66x66) -> B2 ; reads s from B1
#pragma unroll
    for (int it = 0; it < 2; ++it) {
        const int m = tid + 256 * it;
        if (m < 289) {
            const int mi = m / 17, mj = m - mi * 17;
            const int ai0 = mi * 4, aj0 = mj * 4;
            float win[6][6];
#pragma unroll
            for (int r = 0; r < 6; ++r) {
                const float* p = &B1[(ai0 + r) * 72 + aj0];
                float4 a4 = *(const float4*)p;
                float2 b2 = *(const float2*)(p + 4);
                win[r][0] = a4.x; win[r][1] = a4.y; win[r][2] = a4.z;
                win[r][3] = a4.w; win[r][4] = b2.x; win[r][5] = b2.y;
            }
#pragma unroll
            for (int a = 0; a < 4; ++a) {
                float res4[4];
#pragma unroll
                for (int b = 0; b < 4; ++b) {
                    float acc = biasa;
#pragma unroll
                    for (int dy = 0; dy < 3; ++dy)
#pragma unroll
                        for (int dx = 0; dx < 3; ++dx)
                            acc += was[3 * dy + dx] * win[a + dy][b + dx];
                    const int gr = r0 - 1 + ai0 + a, gc = c0 - 1 + aj0 + b;
                    float r1 = 0.f;
                    if ((unsigned)gr < (unsigned)IMG_H && (unsigned)gc < (unsigned)IMG_W)
                        r1 = frelu(acc);
                    res4[b] = r1;
                }
                *(float4*)&B2[(ai0 + a) * 72 + aj0] =
                    make_float4(res4[0], res4[1], res4[2], res4[3]);
            }
        }
    }
    __syncthreads();

    // ---- P6: out 64x64, one 4x4 mini per thread
    {
        const int oi0 = (tid >> 4) << 2, oj0 = (tid & 15) << 2;
        float win[6][6];
#pragma unroll
        for (int r = 0; r < 6; ++r) {
            const float* p = &B2[(oi0 + r) * 72 + oj0];
            float4 a4 = *(const float4*)p;
            float2 b2 = *(const float2*)(p + 4);
            win[r][0] = a4.x; win[r][1] = a4.y; win[r][2] = a4.z;
            win[r][3] = a4.w; win[r][4] = b2.x; win[r][5] = b2.y;
        }
        float* oim = out + (size_t)img * IMG_H * IMG_W;
#pragma unroll
        for (int a = 0; a < 4; ++a) {
            float res4[4];
#pragma unroll
            for (int b = 0; b < 4; ++b) {
                float acc = bd0;
#pragma unroll
                for (int dy = 0; dy < 3; ++dy)
#pragma unroll
                    for (int dx = 0; dx < 3; ++dx)
                        acc += wd9[3 * dy + dx] * win[a + dy][b + dx];
                res4[b] = frelu(acc) * we0 + be0;
            }
            *(float4*)&oim[(size_t)(r0 + oi0 + a) * IMG_W + (c0 + oj0)] =
                make_float4(res4[0], res4[1], res4[2], res4[3]);
        }
    }
}

// ===========================================================================
extern "C" void kernel_launch(void* const* d_in, const int* in_sizes, int n_in,
                              void* d_out, int out_size, void* d_ws, size_t ws_size,
                              hipStream_t stream)
{
    const float* x   = (const float*)d_in[0];
    const float* wa  = (const float*)d_in[1];
    const float* ba  = (const float*)d_in[2];
    const float* ga  = (const float*)d_in[3];
    const float* bta = (const float*)d_in[4];
    const float* ma  = (const float*)d_in[5];
    const float* va  = (const float*)d_in[6];
    const float* wb  = (const float*)d_in[7];
    const float* bb  = (const float*)d_in[8];
    const float* gb  = (const float*)d_in[9];
    const float* btb = (const float*)d_in[10];
    const float* mb  = (const float*)d_in[11];
    const float* vb  = (const float*)d_in[12];
    const float* wc  = (const float*)d_in[13];
    const float* bc  = (const float*)d_in[14];
    const float* gcp = (const float*)d_in[15];
    const float* btc = (const float*)d_in[16];
    const float* mc  = (const float*)d_in[17];
    const float* vc  = (const float*)d_in[18];
    const float* wd  = (const float*)d_in[19];
    const float* bd  = (const float*)d_in[20];
    const float* we  = (const float*)d_in[21];
    const float* be  = (const float*)d_in[22];

    float* outp = (float*)d_out;
    float* M8   = (float*)d_ws;                       // 16 MB
    float* I1S  = M8 + (size_t)NIMG * 128 * IMG_W;    // 2 MB
    float* I2S  = I1S + (size_t)NIMG * IMG_H * 16;    // 2 MB

    k_rowstats<<<dim3(NIMG * 64), dim3(256), 0, stream>>>(
        x, wa, ba, ga, bta, ma, va, M8, I1S);
    k_seed<<<dim3(128), dim3(256), 0, stream>>>(M8, I2S);
    k_tile<<<dim3(NIMG * 256), dim3(256), 0, stream>>>(
        x, I1S, I2S, wa, ba, ga, bta, ma, va, wb, bb, gb, btb, mb, vb,
        wc, bc, gcp, btc, mc, vc, wd, bd, we, be, outp);
}

// Round 4
// 511.861 us; speedup vs baseline: 1.1255x; 1.1255x over previous
//
#include <hip/hip_runtime.h>
#include <math.h>

#define EPS 1e-5f
constexpr int IMG_H = 1024;
constexpr int IMG_W = 1024;
constexpr int NIMG  = 32;

__device__ __forceinline__ float frelu(float v) { return fmaxf(v, 0.f); }

// ===========================================================================
// K1 front: per 8-row strip (4 waves x 2 rows, batch loads):
//   - x1 = relu(bn(conv_wa(x)))
//   - I1S[img][r][j] = i1(r, 32j+3)  (true row suffix-max samples)
//   - M8[img][strip][c] = column max of x1 over the strip's 8 rows
//   - M8part[img][m][c] = column max over rows 3..7 of strip 8(m+1), m=0..14
// ===========================================================================
__global__ __launch_bounds__(256) void k_front(
    const float* __restrict__ x,
    const float* __restrict__ wa, const float* __restrict__ ba,
    const float* __restrict__ ga, const float* __restrict__ bta,
    const float* __restrict__ ma, const float* __restrict__ va,
    float* __restrict__ M8, float* __restrict__ M8part, float* __restrict__ I1S)
{
    const int bid   = blockIdx.x;
    const int img   = bid >> 7;
    const int strip = bid & 127;
    const int lane  = threadIdx.x & 63;
    const int wv    = threadIdx.x >> 6;
    const int rb    = strip * 8 + wv * 2;

    const float scale = ga[0] * rsqrtf(va[0] + EPS);
    float w_s[9];
#pragma unroll
    for (int k = 0; k < 9; ++k) w_s[k] = wa[k] * scale;
    const float bias = (ba[0] - ma[0]) * scale + bta[0];

    const float* xim = x + (size_t)img * IMG_H * IMG_W;

    float4 X[4][4];
#pragma unroll
    for (int ri = 0; ri < 4; ++ri) {
        const int gr = rb - 1 + ri;
        if (gr >= 0 && gr < IMG_H) {
            const float4* rp = (const float4*)(xim + (size_t)gr * IMG_W);
#pragma unroll
            for (int q = 0; q < 4; ++q) X[ri][q] = rp[lane + 64 * q];
        } else {
#pragma unroll
            for (int q = 0; q < 4; ++q) X[ri][q] = make_float4(0.f, 0.f, 0.f, 0.f);
        }
    }

    float4 wm[4], w1r1[4];
#pragma unroll
    for (int rr = 0; rr < 2; ++rr) {
        float4 v[4];
#pragma unroll
        for (int q = 0; q < 4; ++q) {
            float acc0 = bias, acc1 = bias, acc2 = bias, acc3 = bias;
#pragma unroll
            for (int dy = 0; dy < 3; ++dy) {
                float4 C = X[rr + dy][q];
                float Lw = __shfl_up(C.w, 1, 64);
                float Bq = 0.f;
                if (q > 0) Bq = __shfl(X[rr + dy][q - 1].w, 63, 64);
                if (lane == 0) Lw = Bq;
                float Rx = __shfl_down(C.x, 1, 64);
                float Aq = 0.f;
                if (q < 3) Aq = __shfl(X[rr + dy][q + 1].x, 0, 64);
                if (lane == 63) Rx = Aq;
                const float w0 = w_s[3 * dy], w1 = w_s[3 * dy + 1], w2 = w_s[3 * dy + 2];
                acc0 += w0 * Lw  + w1 * C.x + w2 * C.y;
                acc1 += w0 * C.x + w1 * C.y + w2 * C.z;
                acc2 += w0 * C.y + w1 * C.z + w2 * C.w;
                acc3 += w0 * C.z + w1 * C.w + w2 * Rx;
            }
            v[q] = make_float4(frelu(acc0), frelu(acc1), frelu(acc2), frelu(acc3));
        }

        // row suffix-max machinery (verified in r2 k_build_t)
        float sW[4], T4[4], e[4];
#pragma unroll
        for (int q = 0; q < 4; ++q) {
            float s3 = v[q].w;
            float s2 = fmaxf(v[q].z, s3);
            float s1 = fmaxf(v[q].y, s2);
            float s0 = fmaxf(v[q].x, s1);
            sW[q] = s3;
            float mm = s0;
#pragma unroll
            for (int off = 1; off < 64; off <<= 1) {
                float o = __shfl_down(mm, off, 64);
                if (lane + off < 64) mm = fmaxf(mm, o);
            }
            T4[q] = __shfl(mm, 0, 64);
            float ex = __shfl_down(mm, 1, 64);
            if (lane == 63) ex = -INFINITY;
            e[q] = ex;
        }
        float Rr[4];
        Rr[3] = -INFINITY;
        Rr[2] = T4[3];
        Rr[1] = fmaxf(T4[2], Rr[2]);
        Rr[0] = fmaxf(T4[1], Rr[1]);

        if ((lane & 7) == 0) {
            const int r = rb + rr;
#pragma unroll
            for (int q = 0; q < 4; ++q) {
                const float val = fmaxf(sW[q], fmaxf(e[q], Rr[q]));
                I1S[((size_t)img * IMG_H + r) * 32 + (q * 8 + (lane >> 3))] = val;
            }
        }

        if (rr == 0) {
#pragma unroll
            for (int q = 0; q < 4; ++q) wm[q] = v[q];
        } else {
#pragma unroll
            for (int q = 0; q < 4; ++q) {
                wm[q].x = fmaxf(wm[q].x, v[q].x); wm[q].y = fmaxf(wm[q].y, v[q].y);
                wm[q].z = fmaxf(wm[q].z, v[q].z); wm[q].w = fmaxf(wm[q].w, v[q].w);
            }
#pragma unroll
            for (int q = 0; q < 4; ++q) w1r1[q] = v[q];  // row rb+1 values
        }
    }

    __shared__ float4 wmax[5][256];
#pragma unroll
    for (int q = 0; q < 4; ++q) wmax[wv][64 * q + lane] = wm[q];
    if (wv == 1) {
#pragma unroll
        for (int q = 0; q < 4; ++q) wmax[4][64 * q + lane] = w1r1[q];  // strip row 3
    }
    __syncthreads();

    const int tid = threadIdx.x;
    float4 a0 = wmax[0][tid], a1 = wmax[1][tid], a2 = wmax[2][tid], a3 = wmax[3][tid];
    float4 f;
    f.x = fmaxf(fmaxf(a0.x, a1.x), fmaxf(a2.x, a3.x));
    f.y = fmaxf(fmaxf(a0.y, a1.y), fmaxf(a2.y, a3.y));
    f.z = fmaxf(fmaxf(a0.z, a1.z), fmaxf(a2.z, a3.z));
    f.w = fmaxf(fmaxf(a0.w, a1.w), fmaxf(a2.w, a3.w));
    ((float4*)(M8 + ((size_t)img * 128 + strip) * IMG_W))[tid] = f;

    if (strip >= 8 && (strip & 7) == 0) {
        float4 r3v = wmax[4][tid];
        float4 fp;
        fp.x = fmaxf(r3v.x, fmaxf(a2.x, a3.x));
        fp.y = fmaxf(r3v.y, fmaxf(a2.y, a3.y));
        fp.z = fmaxf(r3v.z, fmaxf(a2.z, a3.z));
        fp.w = fmaxf(r3v.w, fmaxf(a2.w, a3.w));
        ((float4*)(M8part + ((size_t)img * 15 + ((strip >> 3) - 1)) * IMG_W))[tid] = fp;
    }
}

// ===========================================================================
// K2: I2S[img][m][c] = max(M8part[m], max over strips >= 8m+9) = colmax of x1
// over rows >= 64m+67.
// ===========================================================================
__global__ __launch_bounds__(256) void k_seed2(
    const float* __restrict__ M8, const float* __restrict__ M8part,
    float* __restrict__ I2S)
{
    const int gid = blockIdx.x * 256 + threadIdx.x;   // 32768
    const int img = gid >> 10;
    const int c   = gid & 1023;
    const float* mp = M8 + (size_t)img * 128 * IMG_W + c;

    float run = 0.f;
#pragma unroll 7
    for (int s = 127; s >= 9; --s) {
        run = fmaxf(run, mp[(size_t)s * IMG_W]);
        if ((s & 7) == 1) {
            const int m = (s - 9) >> 3;
            const size_t o = ((size_t)img * 15 + m) * IMG_W + c;
            I2S[o] = fmaxf(run, M8part[o]);
        }
    }
}

// ===========================================================================
// K3 tile: 64x32 output per block, 6 blocks/CU.
//   P1: x1 window (70x38) -> B1
//   P2: per-wave partial column maxes -> P
//   P3: per-wave bottom-up: i1 (shfl suffix + I1S seed) + i2 (running max +
//       I2S seed); t overwrites B1 in place
//   P4: s  (68x36) -> B2 (reads x inline, L1-resident from P1)
//   P5: a1 (66x34) -> B1
//   P6: out (64x32) -> global
// ===========================================================================
#define PITCH 44
__global__ __launch_bounds__(256, 6) void k_tile(
    const float* __restrict__ x,
    const float* __restrict__ I1S, const float* __restrict__ I2S,
    const float* __restrict__ wa, const float* __restrict__ ba,
    const float* __restrict__ ga, const float* __restrict__ bta,
    const float* __restrict__ ma, const float* __restrict__ va,
    const float* __restrict__ wb, const float* __restrict__ bb,
    const float* __restrict__ gb, const float* __restrict__ btb,
    const float* __restrict__ mb, const float* __restrict__ vb,
    const float* __restrict__ wc, const float* __restrict__ bc,
    const float* __restrict__ gcp, const float* __restrict__ btc,
    const float* __restrict__ mc, const float* __restrict__ vc,
    const float* __restrict__ wd, const float* __restrict__ bd,
    const float* __restrict__ we, const float* __restrict__ be,
    float* __restrict__ out)
{
    __shared__ float B1[70 * PITCH];
    __shared__ float B2[68 * PITCH];
    __shared__ float P[4][PITCH];

    const int bid = blockIdx.x;
    const int img = bid >> 9;
    const int tr  = (bid >> 5) & 15;
    const int tc  = bid & 31;
    const int r0  = tr * 64, c0 = tc * 32;
    const int tid = threadIdx.x;
    const int lane = tid & 63;
    const int wv   = tid >> 6;

    const float* xim = x + (size_t)img * IMG_H * IMG_W;

    // ---- early seed loads (latency hidden under P1)
    float i2sv = 0.f;
    if (tr < 15 && lane < 38) {
        const int col = c0 - 3 + lane;
        if ((unsigned)col < (unsigned)IMG_W)
            i2sv = I2S[((size_t)img * 15 + tr) * IMG_W + col];
    }
    const int g0 = wv * 18;
    const int nrows = (wv == 3) ? 16 : 18;
    float seed1v = 0.f;
    if (lane < nrows && tc < 31) {
        const int row = r0 - 3 + g0 + lane;
        if ((unsigned)row < (unsigned)IMG_H)
            seed1v = I1S[((size_t)img * IMG_H + row) * 32 + (tc + 1)];
    }

    const float sa = ga[0] * rsqrtf(va[0] + EPS);
    float was[9];
#pragma unroll
    for (int k = 0; k < 9; ++k) was[k] = wa[k] * sa;
    const float biasa = (ba[0] - ma[0]) * sa + bta[0];

    const float sb = gb[0] * rsqrtf(vb[0] + EPS);
    float wbs[9];
#pragma unroll
    for (int k = 0; k < 9; ++k) wbs[k] = wb[k] * sb;
    const float biasb = (bb[0] - mb[0]) * sb + btb[0];

    const float sc = gcp[0] * rsqrtf(vc[0] + EPS);
    const float kc = wc[0] * sc;
    const float biasc = (bc[0] - mc[0]) * sc + btc[0];

    float wd9[9];
#pragma unroll
    for (int k = 0; k < 9; ++k) wd9[k] = wd[k];
    const float bd0 = bd[0], we0 = we[0], be0 = be[0];

    // ---- P1: x1 window 70 rows x (38+2) cols, minis 4x4 (18x10=180)
    if (tid < 180) {
        const int mi = tid / 10, mj = tid - mi * 10;
        const int wr0 = mi * 4, wc0 = mj * 4;
        const int gr0 = r0 - 4 + wr0;
        const int gc0 = c0 - 4 + wc0;
        const bool fastC = (gc0 >= 0) && (gc0 + 5 < IMG_W);
        float w[6][6];
#pragma unroll
        for (int rr = 0; rr < 6; ++rr) {
            const int gr = gr0 + rr;
            if ((unsigned)gr < (unsigned)IMG_H) {
                const float* rp = xim + (size_t)gr * IMG_W;
                if (fastC) {
                    float4 a4 = *(const float4*)(rp + gc0);
                    float2 b2 = *(const float2*)(rp + gc0 + 4);
                    w[rr][0] = a4.x; w[rr][1] = a4.y; w[rr][2] = a4.z;
                    w[rr][3] = a4.w; w[rr][4] = b2.x; w[rr][5] = b2.y;
                } else {
#pragma unroll
                    for (int j = 0; j < 6; ++j) {
                        const int gc = gc0 + j;
                        w[rr][j] = ((unsigned)gc < (unsigned)IMG_W) ? rp[gc] : 0.f;
                    }
                }
            } else {
#pragma unroll
                for (int j = 0; j < 6; ++j) w[rr][j] = 0.f;
            }
        }
#pragma unroll
        for (int rr = 0; rr < 4; ++rr) {
            if (wr0 + rr < 70) {
                const int grx = r0 - 3 + wr0 + rr;
                float res4[4];
#pragma unroll
                for (int cc = 0; cc < 4; ++cc) {
                    float acc = biasa;
#pragma unroll
                    for (int dy = 0; dy < 3; ++dy)
#pragma unroll
                        for (int dx = 0; dx < 3; ++dx)
                            acc += was[3 * dy + dx] * w[rr + dy][cc + dx];
                    const int gcx = c0 - 3 + wc0 + cc;
                    float val = 0.f;
                    if ((unsigned)grx < (unsigned)IMG_H && (unsigned)gcx < (unsigned)IMG_W)
                        val = frelu(acc);
                    res4[cc] = val;
                }
                *(float4*)&B1[(wr0 + rr) * PITCH + wc0] =
                    make_float4(res4[0], res4[1], res4[2], res4[3]);
            }
        }
    }
    __syncthreads();

    // ---- P2: per-wave partial column max of its row group
    {
        float pm = 0.f;
        if (lane < 38) {
            for (int k = 0; k < nrows; ++k)
                pm = fmaxf(pm, B1[(g0 + k) * PITCH + lane]);
            P[wv][lane] = pm;
        }
    }
    __syncthreads();

    // ---- P3: bottom-up within group: i1 + i2, t in place
    {
        float run = i2sv;
#pragma unroll
        for (int w2 = 1; w2 < 4; ++w2)
            if (w2 > wv && lane < 38) run = fmaxf(run, P[w2][lane]);
#pragma unroll 6
        for (int k = 0; k < 18; ++k) {
            if (k < nrows) {
                const int lr = nrows - 1 - k;       // local row, bottom-up
                const int wr = g0 + lr;
                const float xv = (lane < 38) ? B1[wr * PITCH + lane] : 0.f;
                float mm = xv;
#pragma unroll
                for (int off = 1; off < 64; off <<= 1) {
                    float o = __shfl_down(mm, off, 64);
                    if (lane + off < 64) mm = fmaxf(mm, o);
                }
                const float sd = __shfl(seed1v, lr, 64);
                const float i1v = fmaxf(mm, sd);
                run = fmaxf(run, xv);
                const int row = r0 - 3 + wr;
                const int col = c0 - 3 + lane;
                const bool inb = ((unsigned)row < (unsigned)IMG_H) &&
                                 ((unsigned)col < (unsigned)IMG_W);
                if (lane < 38)
                    B1[wr * PITCH + lane] = inb ? (i1v + run) : 0.f;
            }
        }
    }
    __syncthreads();

    // ---- P4: s (68x36) -> B2 ; minis 17x9=153
    if (tid < 153) {
        const int mi = tid / 9, mj = tid - mi * 9;
        const int si0 = mi * 4, sj0 = mj * 4;
        float win[6][6];
#pragma unroll
        for (int r = 0; r < 6; ++r) {
            const float* p = &B1[(si0 + r) * PITCH + sj0];
            float4 a4 = *(const float4*)p;
            float2 b2 = *(const float2*)(p + 4);
            win[r][0] = a4.x; win[r][1] = a4.y; win[r][2] = a4.z;
            win[r][3] = a4.w; win[r][4] = b2.x; win[r][5] = b2.y;
        }
#pragma unroll
        for (int a = 0; a < 4; ++a) {
            float res4[4];
#pragma unroll
            for (int b = 0; b < 4; ++b) {
                float acc = biasb;
#pragma unroll
                for (int dy = 0; dy < 3; ++dy)
#pragma unroll
                    for (int dx = 0; dx < 3; ++dx)
                        acc += wbs[3 * dy + dx] * win[a + dy][b + dx];
                const int gr = r0 - 2 + si0 + a, gc = c0 - 2 + sj0 + b;
                float sres = 0.f;
                if ((unsigned)gr < (unsigned)IMG_H && (unsigned)gc < (unsigned)IMG_W) {
                    const float xv = xim[(size_t)gr * IMG_W + gc];
                    sres = frelu(acc + xv * kc + biasc);
                }
                res4[b] = sres;
            }
            *(float4*)&B2[(si0 + a) * PITCH + sj0] =
                make_float4(res4[0], res4[1], res4[2], res4[3]);
        }
    }
    __syncthreads();

    // ---- P5: a1 (66x34) -> B1 ; minis 17x9
    if (tid < 153) {
        const int mi = tid / 9, mj = tid - mi * 9;
        const int ai0 = mi * 4, aj0 = mj * 4;
        float win[6][6];
#pragma unroll
        for (int r = 0; r < 6; ++r) {
            const int rrow = (ai0 + r < 68) ? (ai0 + r) : 67;
            const float* p = &B2[rrow * PITCH + aj0];
            float4 a4 = *(const float4*)p;
            float2 b2 = *(const float2*)(p + 4);
            win[r][0] = a4.x; win[r][1] = a4.y; win[r][2] = a4.z;
            win[r][3] = a4.w; win[r][4] = b2.x; win[r][5] = b2.y;
        }
#pragma unroll
        for (int a = 0; a < 4; ++a) {
            if (ai0 + a < 66) {
                float res4[4];
#pragma unroll
                for (int b = 0; b < 4; ++b) {
                    float acc = biasa;
#pragma unroll
                    for (int dy = 0; dy < 3; ++dy)
#pragma unroll
                        for (int dx = 0; dx < 3; ++dx)
                            acc += was[3 * dy + dx] * win[a + dy][b + dx];
                    const int gr = r0 - 1 + ai0 + a, gc = c0 - 1 + aj0 + b;
                    float r1 = 0.f;
                    if ((unsigned)gr < (unsigned)IMG_H && (unsigned)gc < (unsigned)IMG_W)
                        r1 = frelu(acc);
                    res4[b] = r1;
                }
                *(float4*)&B1[(ai0 + a) * PITCH + aj0] =
                    make_float4(res4[0], res4[1], res4[2], res4[3]);
            }
        }
    }
    __syncthreads();

    // ---- P6: out 64x32, 2x4 mini per thread (32x8 grid = 256)
    {
        const int oi0 = (tid >> 3) * 2, oj0 = (tid & 7) * 4;
        float win[4][6];
#pragma unroll
        for (int r = 0; r < 4; ++r) {
            const float* p = &B1[(oi0 + r) * PITCH + oj0];
            float4 a4 = *(const float4*)p;
            float2 b2 = *(const float2*)(p + 4);
            win[r][0] = a4.x; win[r][1] = a4.y; win[r][2] = a4.z;
            win[r][3] = a4.w; win[r][4] = b2.x; win[r][5] = b2.y;
        }
        float* oim = out + (size_t)img * IMG_H * IMG_W;
#pragma unroll
        for (int a = 0; a < 2; ++a) {
            float res4[4];
#pragma unroll
            for (int b = 0; b < 4; ++b) {
                float acc = bd0;
#pragma unroll
                for (int dy = 0; dy < 3; ++dy)
#pragma unroll
                    for (int dx = 0; dx < 3; ++dx)
                        acc += wd9[3 * dy + dx] * win[a + dy][b + dx];
                res4[b] = frelu(acc) * we0 + be0;
            }
            *(float4*)&oim[(size_t)(r0 + oi0 + a) * IMG_W + (c0 + oj0)] =
                make_float4(res4[0], res4[1], res4[2], res4[3]);
        }
    }
}

// ===========================================================================
extern "C" void kernel_launch(void* const* d_in, const int* in_sizes, int n_in,
                              void* d_out, int out_size, void* d_ws, size_t ws_size,
                              hipStream_t stream)
{
    const float* x   = (const float*)d_in[0];
    const float* wa  = (const float*)d_in[1];
    const float* ba  = (const float*)d_in[2];
    const float* ga  = (const float*)d_in[3];
    const float* bta = (const float*)d_in[4];
    const float* ma  = (const float*)d_in[5];
    const float* va  = (const float*)d_in[6];
    const float* wb  = (const float*)d_in[7];
    const float* bb  = (const float*)d_in[8];
    const float* gb  = (const float*)d_in[9];
    const float* btb = (const float*)d_in[10];
    const float* mb  = (const float*)d_in[11];
    const float* vb  = (const float*)d_in[12];
    const float* wc  = (const float*)d_in[13];
    const float* bc  = (const float*)d_in[14];
    const float* gcp = (const float*)d_in[15];
    const float* btc = (const float*)d_in[16];
    const float* mc  = (const float*)d_in[17];
    const float* vc  = (const float*)d_in[18];
    const float* wd  = (const float*)d_in[19];
    const float* bd  = (const float*)d_in[20];
    const float* we  = (const float*)d_in[21];
    const float* be  = (const float*)d_in[22];

    float* outp   = (float*)d_out;
    float* M8     = (float*)d_ws;                           // 16 MB
    float* M8part = M8 + (size_t)NIMG * 128 * IMG_W;        // 1.9 MB
    float* I1S    = M8part + (size_t)NIMG * 15 * IMG_W;     // 4 MB
    float* I2S    = I1S + (size_t)NIMG * IMG_H * 32;        // 1.9 MB

    k_front<<<dim3(NIMG * 128), dim3(256), 0, stream>>>(
        x, wa, ba, ga, bta, ma, va, M8, M8part, I1S);
    k_seed2<<<dim3(128), dim3(256), 0, stream>>>(M8, M8part, I2S);
    k_tile<<<dim3(NIMG * 16 * 32), dim3(256), 0, stream>>>(
        x, I1S, I2S, wa, ba, ga, bta, ma, va, wb, bb, gb, btb, mb, vb,
        wc, bc, gcp, btc, mc, vc, wd, bd, we, be, outp);
}

// Round 6
// 494.041 us; speedup vs baseline: 1.1661x; 1.0361x over previous
//
#include <hip/hip_runtime.h>
#include <math.h>

#define EPS 1e-5f
constexpr int IMG_H = 1024;
constexpr int IMG_W = 1024;
constexpr int NIMG  = 32;

__device__ __forceinline__ float frelu(float v) { return fmaxf(v, 0.f); }

// ===========================================================================
// K1 front (verbatim from round 4 — verified):
//   x1 = relu(bn(conv_wa(x))); I1S row-suffix samples; M8 strip colmax;
//   M8part partial strip colmax.
// ===========================================================================
__global__ __launch_bounds__(256) void k_front(
    const float* __restrict__ x,
    const float* __restrict__ wa, const float* __restrict__ ba,
    const float* __restrict__ ga, const float* __restrict__ bta,
    const float* __restrict__ ma, const float* __restrict__ va,
    float* __restrict__ M8, float* __restrict__ M8part, float* __restrict__ I1S)
{
    const int bid   = blockIdx.x;
    const int img   = bid >> 7;
    const int strip = bid & 127;
    const int lane  = threadIdx.x & 63;
    const int wv    = threadIdx.x >> 6;
    const int rb    = strip * 8 + wv * 2;

    const float scale = ga[0] * rsqrtf(va[0] + EPS);
    float w_s[9];
#pragma unroll
    for (int k = 0; k < 9; ++k) w_s[k] = wa[k] * scale;
    const float bias = (ba[0] - ma[0]) * scale + bta[0];

    const float* xim = x + (size_t)img * IMG_H * IMG_W;

    float4 X[4][4];
#pragma unroll
    for (int ri = 0; ri < 4; ++ri) {
        const int gr = rb - 1 + ri;
        if (gr >= 0 && gr < IMG_H) {
            const float4* rp = (const float4*)(xim + (size_t)gr * IMG_W);
#pragma unroll
            for (int q = 0; q < 4; ++q) X[ri][q] = rp[lane + 64 * q];
        } else {
#pragma unroll
            for (int q = 0; q < 4; ++q) X[ri][q] = make_float4(0.f, 0.f, 0.f, 0.f);
        }
    }

    float4 wm[4], w1r1[4];
#pragma unroll
    for (int rr = 0; rr < 2; ++rr) {
        float4 v[4];
#pragma unroll
        for (int q = 0; q < 4; ++q) {
            float acc0 = bias, acc1 = bias, acc2 = bias, acc3 = bias;
#pragma unroll
            for (int dy = 0; dy < 3; ++dy) {
                float4 C = X[rr + dy][q];
                float Lw = __shfl_up(C.w, 1, 64);
                float Bq = 0.f;
                if (q > 0) Bq = __shfl(X[rr + dy][q - 1].w, 63, 64);
                if (lane == 0) Lw = Bq;
                float Rx = __shfl_down(C.x, 1, 64);
                float Aq = 0.f;
                if (q < 3) Aq = __shfl(X[rr + dy][q + 1].x, 0, 64);
                if (lane == 63) Rx = Aq;
                const float w0 = w_s[3 * dy], w1 = w_s[3 * dy + 1], w2 = w_s[3 * dy + 2];
                acc0 += w0 * Lw  + w1 * C.x + w2 * C.y;
                acc1 += w0 * C.x + w1 * C.y + w2 * C.z;
                acc2 += w0 * C.y + w1 * C.z + w2 * C.w;
                acc3 += w0 * C.z + w1 * C.w + w2 * Rx;
            }
            v[q] = make_float4(frelu(acc0), frelu(acc1), frelu(acc2), frelu(acc3));
        }

        float sW[4], T4[4], e[4];
#pragma unroll
        for (int q = 0; q < 4; ++q) {
            float s3 = v[q].w;
            float s2 = fmaxf(v[q].z, s3);
            float s1 = fmaxf(v[q].y, s2);
            float s0 = fmaxf(v[q].x, s1);
            sW[q] = s3;
            float mm = s0;
#pragma unroll
            for (int off = 1; off < 64; off <<= 1) {
                float o = __shfl_down(mm, off, 64);
                if (lane + off < 64) mm = fmaxf(mm, o);
            }
            T4[q] = __shfl(mm, 0, 64);
            float ex = __shfl_down(mm, 1, 64);
            if (lane == 63) ex = -INFINITY;
            e[q] = ex;
        }
        float Rr[4];
        Rr[3] = -INFINITY;
        Rr[2] = T4[3];
        Rr[1] = fmaxf(T4[2], Rr[2]);
        Rr[0] = fmaxf(T4[1], Rr[1]);

        if ((lane & 7) == 0) {
            const int r = rb + rr;
#pragma unroll
            for (int q = 0; q < 4; ++q) {
                const float val = fmaxf(sW[q], fmaxf(e[q], Rr[q]));
                I1S[((size_t)img * IMG_H + r) * 32 + (q * 8 + (lane >> 3))] = val;
            }
        }

        if (rr == 0) {
#pragma unroll
            for (int q = 0; q < 4; ++q) wm[q] = v[q];
        } else {
#pragma unroll
            for (int q = 0; q < 4; ++q) {
                wm[q].x = fmaxf(wm[q].x, v[q].x); wm[q].y = fmaxf(wm[q].y, v[q].y);
                wm[q].z = fmaxf(wm[q].z, v[q].z); wm[q].w = fmaxf(wm[q].w, v[q].w);
            }
#pragma unroll
            for (int q = 0; q < 4; ++q) w1r1[q] = v[q];
        }
    }

    __shared__ float4 wmax[5][256];
#pragma unroll
    for (int q = 0; q < 4; ++q) wmax[wv][64 * q + lane] = wm[q];
    if (wv == 1) {
#pragma unroll
        for (int q = 0; q < 4; ++q) wmax[4][64 * q + lane] = w1r1[q];
    }
    __syncthreads();

    const int tid = threadIdx.x;
    float4 a0 = wmax[0][tid], a1 = wmax[1][tid], a2 = wmax[2][tid], a3 = wmax[3][tid];
    float4 f;
    f.x = fmaxf(fmaxf(a0.x, a1.x), fmaxf(a2.x, a3.x));
    f.y = fmaxf(fmaxf(a0.y, a1.y), fmaxf(a2.y, a3.y));
    f.z = fmaxf(fmaxf(a0.z, a1.z), fmaxf(a2.z, a3.z));
    f.w = fmaxf(fmaxf(a0.w, a1.w), fmaxf(a2.w, a3.w));
    ((float4*)(M8 + ((size_t)img * 128 + strip) * IMG_W))[tid] = f;

    if (strip >= 8 && (strip & 7) == 0) {
        float4 r3v = wmax[4][tid];
        float4 fp;
        fp.x = fmaxf(r3v.x, fmaxf(a2.x, a3.x));
        fp.y = fmaxf(r3v.y, fmaxf(a2.y, a3.y));
        fp.z = fmaxf(r3v.z, fmaxf(a2.z, a3.z));
        fp.w = fmaxf(r3v.w, fmaxf(a2.w, a3.w));
        ((float4*)(M8part + ((size_t)img * 15 + ((strip >> 3) - 1)) * IMG_W))[tid] = fp;
    }
}

// ===========================================================================
// K2 (verbatim from round 4 — verified)
// ===========================================================================
__global__ __launch_bounds__(256) void k_seed2(
    const float* __restrict__ M8, const float* __restrict__ M8part,
    float* __restrict__ I2S)
{
    const int gid = blockIdx.x * 256 + threadIdx.x;
    const int img = gid >> 10;
    const int c   = gid & 1023;
    const float* mp = M8 + (size_t)img * 128 * IMG_W + c;

    float run = 0.f;
#pragma unroll 7
    for (int s = 127; s >= 9; --s) {
        run = fmaxf(run, mp[(size_t)s * IMG_W]);
        if ((s & 7) == 1) {
            const int m = (s - 9) >> 3;
            const size_t o = ((size_t)img * 15 + m) * IMG_W + c;
            I2S[o] = fmaxf(run, M8part[o]);
        }
    }
}

// ===========================================================================
// K3 tile v2: 64x32 output per block; x staged to LDS once; interior fast
// path (82% of blocks skip all masking).
// LDS: BA 72x44 (x, then s), B1 70x44 (x1 -> t -> a1), Pm 4x44. ~25 KB.
// ===========================================================================
#define PITCH 44
__global__ __launch_bounds__(256, 6) void k_tile(
    const float* __restrict__ x,
    const float* __restrict__ I1S, const float* __restrict__ I2S,
    const float* __restrict__ wa, const float* __restrict__ ba,
    const float* __restrict__ ga, const float* __restrict__ bta,
    const float* __restrict__ ma, const float* __restrict__ va,
    const float* __restrict__ wb, const float* __restrict__ bb,
    const float* __restrict__ gb, const float* __restrict__ btb,
    const float* __restrict__ mb, const float* __restrict__ vb,
    const float* __restrict__ wc, const float* __restrict__ bc,
    const float* __restrict__ gcp, const float* __restrict__ btc,
    const float* __restrict__ mc, const float* __restrict__ vc,
    const float* __restrict__ wd, const float* __restrict__ bd,
    const float* __restrict__ we, const float* __restrict__ be,
    float* __restrict__ out)
{
    __shared__ float BA[72 * PITCH];
    __shared__ float B1[70 * PITCH];
    __shared__ float Pm[4][PITCH];

    const int bid = blockIdx.x;
    const int img = bid >> 9;
    const int tr  = (bid >> 5) & 15;
    const int tc  = bid & 31;
    const int r0  = tr * 64, c0 = tc * 32;
    const int tid = threadIdx.x;
    const int lane = tid & 63;
    const int wv   = tid >> 6;
    const bool intr = (tr >= 1) && (tr <= 14) && (tc >= 1) && (tc <= 30);

    const float* xim = x + (size_t)img * IMG_H * IMG_W;

    // ---- early seed loads (latency hidden under staging)
    float i2sv = 0.f;
    if (tr < 15 && lane < 38) {
        const int col = c0 - 3 + lane;
        if ((unsigned)col < (unsigned)IMG_W)
            i2sv = I2S[((size_t)img * 15 + tr) * IMG_W + col];
    }
    const int g0 = wv * 18;
    const int nrows = (wv == 3) ? 16 : 18;
    float seed1v = 0.f;
    if (lane < nrows && tc < 31) {
        const int row = r0 - 3 + g0 + lane;
        if ((unsigned)row < (unsigned)IMG_H)
            seed1v = I1S[((size_t)img * IMG_H + row) * 32 + (tc + 1)];
    }

    const float sa = ga[0] * rsqrtf(va[0] + EPS);
    float was[9];
#pragma unroll
    for (int k = 0; k < 9; ++k) was[k] = wa[k] * sa;
    const float biasa = (ba[0] - ma[0]) * sa + bta[0];

    const float sb = gb[0] * rsqrtf(vb[0] + EPS);
    float wbs[9];
#pragma unroll
    for (int k = 0; k < 9; ++k) wbs[k] = wb[k] * sb;
    const float biasb = (bb[0] - mb[0]) * sb + btb[0];

    const float sc = gcp[0] * rsqrtf(vc[0] + EPS);
    const float kc = wc[0] * sc;
    const float biasc = (bc[0] - mc[0]) * sc + btc[0];

    float wd9[9];
#pragma unroll
    for (int k = 0; k < 9; ++k) wd9[k] = wd[k];
    const float bd0 = bd[0], we0 = we[0], be0 = be[0];

    // ---- P0: stage x rows r0-4..r0+67, cols c0-4..c0+35 -> BA (72x40 valid)
    if (intr) {
        const float* xs = xim + (size_t)(r0 - 4) * IMG_W + (c0 - 4);
#pragma unroll
        for (int it = 0; it < 3; ++it) {
            const int f = tid + it * 256;
            if (f < 720) {
                const int row = f / 10, cg = f - row * 10;
                float4 v = *(const float4*)(xs + (size_t)row * IMG_W + 4 * cg);
                *(float4*)&BA[row * PITCH + 4 * cg] = v;
            }
        }
    } else {
#pragma unroll
        for (int it = 0; it < 3; ++it) {
            const int f = tid + it * 256;
            if (f < 720) {
                const int row = f / 10, cg = f - row * 10;
                const int gr = r0 - 4 + row;
                const int gc = c0 - 4 + 4 * cg;
                float4 v = make_float4(0.f, 0.f, 0.f, 0.f);
                if ((unsigned)gr < (unsigned)IMG_H) {
                    const float* rp = xim + (size_t)gr * IMG_W;
                    if (gc >= 0 && gc + 3 < IMG_W) {
                        v = *(const float4*)(rp + gc);
                    } else {
                        if ((unsigned)(gc)     < (unsigned)IMG_W) v.x = rp[gc];
                        if ((unsigned)(gc + 1) < (unsigned)IMG_W) v.y = rp[gc + 1];
                        if ((unsigned)(gc + 2) < (unsigned)IMG_W) v.z = rp[gc + 2];
                        if ((unsigned)(gc + 3) < (unsigned)IMG_W) v.w = rp[gc + 3];
                    }
                }
                *(float4*)&BA[row * PITCH + 4 * cg] = v;
            }
        }
    }
    __syncthreads();

    // ---- P1: x1 (70x38) -> B1, conv from BA
    if (tid < 180) {
        const int mi = tid / 10, mj = tid - mi * 10;
        const int wr0 = mi * 4, wc0 = mj * 4;
        float w[6][6];
#pragma unroll
        for (int r = 0; r < 6; ++r) {
            const int br = (wr0 + r < 72) ? (wr0 + r) : 71;
            const float* p = &BA[br * PITCH + wc0];
            float4 a4 = *(const float4*)p;
            float2 b2 = *(const float2*)(p + 4);
            w[r][0] = a4.x; w[r][1] = a4.y; w[r][2] = a4.z;
            w[r][3] = a4.w; w[r][4] = b2.x; w[r][5] = b2.y;
        }
#pragma unroll
        for (int rr = 0; rr < 4; ++rr) {
            if (wr0 + rr < 70) {
                float res4[4];
#pragma unroll
                for (int cc = 0; cc < 4; ++cc) {
                    float acc = biasa;
#pragma unroll
                    for (int dy = 0; dy < 3; ++dy)
#pragma unroll
                        for (int dx = 0; dx < 3; ++dx)
                            acc += was[3 * dy + dx] * w[rr + dy][cc + dx];
                    if (intr) {
                        res4[cc] = frelu(acc);
                    } else {
                        const int grx = r0 - 3 + wr0 + rr;
                        const int gcx = c0 - 3 + wc0 + cc;
                        float val = 0.f;
                        if ((unsigned)grx < (unsigned)IMG_H && (unsigned)gcx < (unsigned)IMG_W)
                            val = frelu(acc);
                        res4[cc] = val;
                    }
                }
                *(float4*)&B1[(wr0 + rr) * PITCH + wc0] =
                    make_float4(res4[0], res4[1], res4[2], res4[3]);
            }
        }
    }
    __syncthreads();

    // ---- P2: per-wave partial column max (verbatim r4)
    {
        float pm = 0.f;
        if (lane < 38) {
            for (int k = 0; k < nrows; ++k)
                pm = fmaxf(pm, B1[(g0 + k) * PITCH + lane]);
            Pm[wv][lane] = pm;
        }
    }
    __syncthreads();

    // ---- P3: bottom-up i1 + i2, t in place (verbatim r4)
    {
        float run = i2sv;
#pragma unroll
        for (int w2 = 1; w2 < 4; ++w2)
            if (w2 > wv && lane < 38) run = fmaxf(run, Pm[w2][lane]);
#pragma unroll 6
        for (int k = 0; k < 18; ++k) {
            if (k < nrows) {
                const int lr = nrows - 1 - k;
                const int wr = g0 + lr;
                const float xv = (lane < 38) ? B1[wr * PITCH + lane] : 0.f;
                float mm = xv;
#pragma unroll
                for (int off = 1; off < 64; off <<= 1) {
                    float o = __shfl_down(mm, off, 64);
                    if (lane + off < 64) mm = fmaxf(mm, o);
                }
                const float sd = __shfl(seed1v, lr, 64);
                const float i1v = fmaxf(mm, sd);
                run = fmaxf(run, xv);
                const int row = r0 - 3 + wr;
                const int col = c0 - 3 + lane;
                const bool inb = ((unsigned)row < (unsigned)IMG_H) &&
                                 ((unsigned)col < (unsigned)IMG_W);
                if (lane < 38)
                    B1[wr * PITCH + lane] = inb ? (i1v + run) : 0.f;
            }
        }
    }
    __syncthreads();

    // ---- P4a: pre-read x window for s from BA (BA stable since staging)
    float xr[16];
    if (tid < 153) {
        const int mi = tid / 9, mj = tid - mi * 9;
        const int si0 = mi * 4, sj0 = mj * 4;
#pragma unroll
        for (int a = 0; a < 4; ++a) {
            const float* p = &BA[(si0 + 2 + a) * PITCH + sj0 + 2];
            float2 u = *(const float2*)p;
            float2 v = *(const float2*)(p + 2);
            xr[a * 4 + 0] = u.x; xr[a * 4 + 1] = u.y;
            xr[a * 4 + 2] = v.x; xr[a * 4 + 3] = v.y;
        }
    }
    __syncthreads();

    // ---- P4b: s (68x36) -> BA (overwrites x); reads t from B1 + xr regs
    if (tid < 153) {
        const int mi = tid / 9, mj = tid - mi * 9;
        const int si0 = mi * 4, sj0 = mj * 4;
        float w[6][6];
#pragma unroll
        for (int r = 0; r < 6; ++r) {
            const float* p = &B1[(si0 + r) * PITCH + sj0];
            float4 a4 = *(const float4*)p;
            float2 b2 = *(const float2*)(p + 4);
            w[r][0] = a4.x; w[r][1] = a4.y; w[r][2] = a4.z;
            w[r][3] = a4.w; w[r][4] = b2.x; w[r][5] = b2.y;
        }
#pragma unroll
        for (int a = 0; a < 4; ++a) {
            float res4[4];
#pragma unroll
            for (int b = 0; b < 4; ++b) {
                float acc = biasb + biasc;
#pragma unroll
                for (int dy = 0; dy < 3; ++dy)
#pragma unroll
                    for (int dx = 0; dx < 3; ++dx)
                        acc += wbs[3 * dy + dx] * w[a + dy][b + dx];
                acc += xr[a * 4 + b] * kc;
                if (intr) {
                    res4[b] = frelu(acc);
                } else {
                    const int gr = r0 - 2 + si0 + a, gc = c0 - 2 + sj0 + b;
                    float sres = 0.f;
                    if ((unsigned)gr < (unsigned)IMG_H && (unsigned)gc < (unsigned)IMG_W)
                        sres = frelu(acc);
                    res4[b] = sres;
                }
            }
            *(float4*)&BA[(si0 + a) * PITCH + sj0] =
                make_float4(res4[0], res4[1], res4[2], res4[3]);
        }
    }
    __syncthreads();

    // ---- P5: a1 (66x34) -> B1 ; reads s from BA
    if (tid < 153) {
        const int mi = tid / 9, mj = tid - mi * 9;
        const int ai0 = mi * 4, aj0 = mj * 4;
        float w[6][6];
#pragma unroll
        for (int r = 0; r < 6; ++r) {
            const int rrow = (ai0 + r < 68) ? (ai0 + r) : 67;
            const float* p = &BA[rrow * PITCH + aj0];
            float4 a4 = *(const float4*)p;
            float2 b2 = *(const float2*)(p + 4);
            w[r][0] = a4.x; w[r][1] = a4.y; w[r][2] = a4.z;
            w[r][3] = a4.w; w[r][4] = b2.x; w[r][5] = b2.y;
        }
#pragma unroll
        for (int a = 0; a < 4; ++a) {
            if (ai0 + a < 66) {
                float res4[4];
#pragma unroll
                for (int b = 0; b < 4; ++b) {
                    float acc = biasa;
#pragma unroll
                    for (int dy = 0; dy < 3; ++dy)
#pragma unroll
                        for (int dx = 0; dx < 3; ++dx)
                            acc += was[3 * dy + dx] * w[a + dy][b + dx];
                    if (intr) {
                        res4[b] = frelu(acc);
                    } else {
                        const int gr = r0 - 1 + ai0 + a, gc = c0 - 1 + aj0 + b;
                        float r1 = 0.f;
                        if ((unsigned)gr < (unsigned)IMG_H && (unsigned)gc < (unsigned)IMG_W)
                            r1 = frelu(acc);
                        res4[b] = r1;
                    }
                }
                *(float4*)&B1[(ai0 + a) * PITCH + aj0] =
                    make_float4(res4[0], res4[1], res4[2], res4[3]);
            }
        }
    }
    __syncthreads();

    // ---- P6: out 64x32, 2x4 mini per thread (verbatim r4)
    {
        const int oi0 = (tid >> 3) * 2, oj0 = (tid & 7) * 4;
        float w[4][6];
#pragma unroll
        for (int r = 0; r < 4; ++r) {
            const float* p = &B1[(oi0 + r) * PITCH + oj0];
            float4 a4 = *(const float4*)p;
            float2 b2 = *(const float2*)(p + 4);
            w[r][0] = a4.x; w[r][1] = a4.y; w[r][2] = a4.z;
            w[r][3] = a4.w; w[r][4] = b2.x; w[r][5] = b2.y;
        }
        float* oim = out + (size_t)img * IMG_H * IMG_W;
#pragma unroll
        for (int a = 0; a < 2; ++a) {
            float res4[4];
#pragma unroll
            for (int b = 0; b < 4; ++b) {
                float acc = bd0;
#pragma unroll
                for (int dy = 0; dy < 3; ++dy)
#pragma unroll
                    for (int dx = 0; dx < 3; ++dx)
                        acc += wd9[3 * dy + dx] * w[a + dy][b + dx];
                res4[b] = frelu(acc) * we0 + be0;
            }
            *(float4*)&oim[(size_t)(r0 + oi0 + a) * IMG_W + (c0 + oj0)] =
                make_float4(res4[0], res4[1], res4[2], res4[3]);
        }
    }
}

// ===========================================================================
extern "C" void kernel_launch(void* const* d_in, const int* in_sizes, int n_in,
                              void* d_out, int out_size, void* d_ws, size_t ws_size,
                              hipStream_t stream)
{
    const float* x   = (const float*)d_in[0];
    const float* wa  = (const float*)d_in[1];
    const float* ba  = (const float*)d_in[2];
    const float* ga  = (const float*)d_in[3];
    const float* bta = (const float*)d_in[4];
    const float* ma  = (const float*)d_in[5];
    const float* va  = (const float*)d_in[6];
    const float* wb  = (const float*)d_in[7];
    const float* bb  = (const float*)d_in[8];
    const float* gb  = (const float*)d_in[9];
    const float* btb = (const float*)d_in[10];
    const float* mb  = (const float*)d_in[11];
    const float* vb  = (const float*)d_in[12];
    const float* wc  = (const float*)d_in[13];
    const float* bc  = (const float*)d_in[14];
    const float* gcp = (const float*)d_in[15];
    const float* btc = (const float*)d_in[16];
    const float* mc  = (const float*)d_in[17];
    const float* vc  = (const float*)d_in[18];
    const float* wd  = (const float*)d_in[19];
    const float* bd  = (const float*)d_in[20];
    const float* we  = (const float*)d_in[21];
    const float* be  = (const float*)d_in[22];

    float* outp   = (float*)d_out;
    float* M8     = (float*)d_ws;                           // 16 MB
    float* M8part = M8 + (size_t)NIMG * 128 * IMG_W;        // 1.9 MB
    float* I1S    = M8part + (size_t)NIMG * 15 * IMG_W;     // 4 MB
    float* I2S    = I1S + (size_t)NIMG * IMG_H * 32;        // 1.9 MB

    k_front<<<dim3(NIMG * 128), dim3(256), 0, stream>>>(
        x, wa, ba, ga, bta, ma, va, M8, M8part, I1S);
    k_seed2<<<dim3(128), dim3(256), 0, stream>>>(M8, M8part, I2S);
    k_tile<<<dim3(NIMG * 16 * 32), dim3(256), 0, stream>>>(
        x, I1S, I2S, wa, ba, ga, bta, ma, va, wb, bb, gb, btb, mb, vb,
        wc, bc, gcp, btc, mc, vc, wd, bd, we, be, outp);
}